// Round 1
// baseline (155.753 us; speedup 1.0000x reference)
//
#include <hip/hip_runtime.h>

#define NTYPES 11
#define BLOCK  256
#define ITEMS  16
#define CHUNK  (BLOCK * ITEMS)   // 4096 atoms per block

// ---------------------------------------------------------------------------
// Kernel 1: per-block per-type histogram.
// bc[t*B + b] = number of atoms of type t in block b's chunk.
// Assumes N % ITEMS == 0 (4,000,000 = 16*250,000), so each thread's run of 16
// atoms is entirely in-bounds or entirely out-of-bounds.
// ---------------------------------------------------------------------------
__global__ __launch_bounds__(BLOCK) void hist_kernel(
    const int* __restrict__ types, int N, int B, int* __restrict__ bc) {
  __shared__ int shCnt[NTYPES];
  const int tid = threadIdx.x;
  const int b = blockIdx.x;
  if (tid < NTYPES) shCnt[tid] = 0;
  __syncthreads();

  const int run = b * CHUNK + tid * ITEMS;
  int cnt[NTYPES];
#pragma unroll
  for (int t = 0; t < NTYPES; ++t) cnt[t] = 0;

  if (run < N) {
    const int4* p = (const int4*)(types + run);
    int4 a0 = p[0], a1 = p[1], a2 = p[2], a3 = p[3];
    int ty[ITEMS] = {a0.x, a0.y, a0.z, a0.w, a1.x, a1.y, a1.z, a1.w,
                     a2.x, a2.y, a2.z, a2.w, a3.x, a3.y, a3.z, a3.w};
#pragma unroll
    for (int k = 0; k < ITEMS; ++k) {
#pragma unroll
      for (int t = 0; t < NTYPES; ++t) cnt[t] += (ty[k] == t) ? 1 : 0;
    }
  }

  const int lane = tid & 63;
#pragma unroll
  for (int t = 0; t < NTYPES; ++t) {
    int v = cnt[t];
    for (int o = 32; o >= 1; o >>= 1) v += __shfl_down(v, o);
    if (lane == 0) atomicAdd(&shCnt[t], v);
  }
  __syncthreads();
  if (tid < NTYPES) bc[tid * B + b] = shCnt[tid];
}

// ---------------------------------------------------------------------------
// Kernel 2: one block. For each type, exclusive scan of bc over blocks ->
// scanOut; totals -> counts; exclusive scan over types -> offs. Writes
// counts/offsets as FLOATS into the tail of d_out.
// Requires B <= 1024 (B = 977 here).
// ---------------------------------------------------------------------------
__global__ __launch_bounds__(1024) void scan_kernel(
    const int* __restrict__ bc, int B, int* __restrict__ scanOut,
    int* __restrict__ offs, float* __restrict__ outTail) {
  __shared__ int wtot[16];
  __shared__ int totals[NTYPES];
  const int tid = threadIdx.x;
  const int lane = tid & 63;
  const int wave = tid >> 6;

  for (int t = 0; t < NTYPES; ++t) {
    const int x = (tid < B) ? bc[t * B + tid] : 0;
    int incl = x;
#pragma unroll
    for (int o = 1; o < 64; o <<= 1) {
      int v = __shfl_up(incl, o);
      if (lane >= o) incl += v;
    }
    if (lane == 63) wtot[wave] = incl;
    __syncthreads();
    if (wave == 0) {
      int y = (lane < 16) ? wtot[lane] : 0;
#pragma unroll
      for (int o = 1; o < 16; o <<= 1) {
        int v = __shfl_up(y, o);
        if (lane >= o) y += v;
      }
      if (lane < 16) wtot[lane] = y;
    }
    __syncthreads();
    incl += (wave > 0) ? wtot[wave - 1] : 0;
    if (tid < B) scanOut[t * B + tid] = incl - x;
    if (tid == 1023) totals[t] = incl;
    __syncthreads();
  }

  if (tid == 0) {
    int off = 0;
    for (int t = 0; t < NTYPES; ++t) {
      const int c = totals[t];
      offs[t] = off;
      outTail[t] = (float)c;            // counts (as float values)
      outTail[NTYPES + t] = (float)off; // offsets (as float values)
      off += c;
    }
  }
}

// ---------------------------------------------------------------------------
// Kernel 3: stable scatter. Each thread handles 16 consecutive atoms; rank =
// type offset + block base (scanOut) + wave base + lane-exclusive-scan +
// within-thread order.
// ---------------------------------------------------------------------------
__global__ __launch_bounds__(BLOCK) void scatter_kernel(
    const float* __restrict__ coords, const int* __restrict__ types,
    const int* __restrict__ scanOut, const int* __restrict__ offs, int N,
    int B, float* __restrict__ out) {
  const int tid = threadIdx.x;
  const int b = blockIdx.x;
  const int lane = tid & 63;
  const int wave = tid >> 6;
  const int run = b * CHUNK + tid * ITEMS;
  const bool active = (run < N);

  int ty[ITEMS];
  int cnt[NTYPES];
#pragma unroll
  for (int t = 0; t < NTYPES; ++t) cnt[t] = 0;
#pragma unroll
  for (int k = 0; k < ITEMS; ++k) ty[k] = -1;

  if (active) {
    const int4* p = (const int4*)(types + run);
    int4 a0 = p[0], a1 = p[1], a2 = p[2], a3 = p[3];
    int tt[ITEMS] = {a0.x, a0.y, a0.z, a0.w, a1.x, a1.y, a1.z, a1.w,
                     a2.x, a2.y, a2.z, a2.w, a3.x, a3.y, a3.z, a3.w};
#pragma unroll
    for (int k = 0; k < ITEMS; ++k) ty[k] = tt[k];
#pragma unroll
    for (int k = 0; k < ITEMS; ++k) {
#pragma unroll
      for (int t = 0; t < NTYPES; ++t) cnt[t] += (ty[k] == t) ? 1 : 0;
    }
  }

  __shared__ int wtot[NTYPES][4];
  int rank[NTYPES];
#pragma unroll
  for (int t = 0; t < NTYPES; ++t) {
    int incl = cnt[t];
#pragma unroll
    for (int o = 1; o < 64; o <<= 1) {
      int v = __shfl_up(incl, o);
      if (lane >= o) incl += v;
    }
    if (lane == 63) wtot[t][wave] = incl;
    rank[t] = incl - cnt[t];  // exclusive within wave
  }
  __syncthreads();
#pragma unroll
  for (int t = 0; t < NTYPES; ++t) {
    int wb = 0;
#pragma unroll
    for (int w = 0; w < 3; ++w) wb += (w < wave) ? wtot[t][w] : 0;
    rank[t] += wb + offs[t] + scanOut[t * B + b];
  }

  if (active) {
    const float4* cp = (const float4*)(coords + (size_t)run * 3);
    float c[ITEMS * 3];
#pragma unroll
    for (int q = 0; q < 12; ++q) {
      float4 v = cp[q];
      c[4 * q + 0] = v.x;
      c[4 * q + 1] = v.y;
      c[4 * q + 2] = v.z;
      c[4 * q + 3] = v.w;
    }
#pragma unroll
    for (int k = 0; k < ITEMS; ++k) {
      const int t0 = ty[k];
      int dst = 0;
#pragma unroll
      for (int t = 0; t < NTYPES; ++t) {
        if (t0 == t) {
          dst = rank[t];
          rank[t] += 1;
        }
      }
      out[3 * (size_t)dst + 0] = c[3 * k + 0];
      out[3 * (size_t)dst + 1] = c[3 * k + 1];
      out[3 * (size_t)dst + 2] = c[3 * k + 2];
    }
  }
}

extern "C" void kernel_launch(void* const* d_in, const int* in_sizes, int n_in,
                              void* d_out, int out_size, void* d_ws,
                              size_t ws_size, hipStream_t stream) {
  const float* coords = (const float*)d_in[0];
  const int* types = (const int*)d_in[1];
  const int N = in_sizes[1];  // 4,000,000 atoms
  const int B = (N + CHUNK - 1) / CHUNK;  // 977 blocks

  int* bc = (int*)d_ws;             // [NTYPES * B]
  int* scanOut = bc + NTYPES * B;   // [NTYPES * B]
  int* offs = scanOut + NTYPES * B; // [NTYPES]
  float* out = (float*)d_out;
  float* outTail = out + (size_t)3 * N;  // counts then offsets, as floats

  hist_kernel<<<B, BLOCK, 0, stream>>>(types, N, B, bc);
  scan_kernel<<<1, 1024, 0, stream>>>(bc, B, scanOut, offs, outTail);
  scatter_kernel<<<B, BLOCK, 0, stream>>>(coords, types, scanOut, offs, N, B,
                                          out);
}

// Round 2
// 140.159 us; speedup vs baseline: 1.1113x; 1.1113x over previous
//
#include <hip/hip_runtime.h>

#define NTYPES 11
#define BLOCK  256
#define ITEMS  16
#define CHUNK  (BLOCK * ITEMS)   // 4096 atoms per block

// ---------------------------------------------------------------------------
// Kernel 1: per-block per-type histogram.
// bc[t*B + b] = number of atoms of type t in block b's chunk.
// ---------------------------------------------------------------------------
__global__ __launch_bounds__(BLOCK) void hist_kernel(
    const int* __restrict__ types, int N, int B, int* __restrict__ bc) {
  __shared__ int shCnt[NTYPES];
  const int tid = threadIdx.x;
  const int b = blockIdx.x;
  if (tid < NTYPES) shCnt[tid] = 0;
  __syncthreads();

  const int run = b * CHUNK + tid * ITEMS;
  int cnt[NTYPES];
#pragma unroll
  for (int t = 0; t < NTYPES; ++t) cnt[t] = 0;

  if (run < N) {
    const int4* p = (const int4*)(types + run);
    int4 a0 = p[0], a1 = p[1], a2 = p[2], a3 = p[3];
    int ty[ITEMS] = {a0.x, a0.y, a0.z, a0.w, a1.x, a1.y, a1.z, a1.w,
                     a2.x, a2.y, a2.z, a2.w, a3.x, a3.y, a3.z, a3.w};
#pragma unroll
    for (int k = 0; k < ITEMS; ++k) {
#pragma unroll
      for (int t = 0; t < NTYPES; ++t) cnt[t] += (ty[k] == t) ? 1 : 0;
    }
  }

  const int lane = tid & 63;
#pragma unroll
  for (int t = 0; t < NTYPES; ++t) {
    int v = cnt[t];
    for (int o = 32; o >= 1; o >>= 1) v += __shfl_down(v, o);
    if (lane == 0) atomicAdd(&shCnt[t], v);
  }
  __syncthreads();
  if (tid < NTYPES) bc[tid * B + b] = shCnt[tid];
}

// ---------------------------------------------------------------------------
// Kernel 2: one block. Per-type exclusive scan over blocks; type totals ->
// counts; exclusive scan over types -> offs. Writes counts/offsets as FLOATS
// into the tail of d_out. Requires B <= 1024 (B = 977 here).
// ---------------------------------------------------------------------------
__global__ __launch_bounds__(1024) void scan_kernel(
    const int* __restrict__ bc, int B, int* __restrict__ scanOut,
    int* __restrict__ offs, float* __restrict__ outTail) {
  __shared__ int wtot[16];
  __shared__ int totals[NTYPES];
  const int tid = threadIdx.x;
  const int lane = tid & 63;
  const int wave = tid >> 6;

  for (int t = 0; t < NTYPES; ++t) {
    const int x = (tid < B) ? bc[t * B + tid] : 0;
    int incl = x;
#pragma unroll
    for (int o = 1; o < 64; o <<= 1) {
      int v = __shfl_up(incl, o);
      if (lane >= o) incl += v;
    }
    if (lane == 63) wtot[wave] = incl;
    __syncthreads();
    if (wave == 0) {
      int y = (lane < 16) ? wtot[lane] : 0;
#pragma unroll
      for (int o = 1; o < 16; o <<= 1) {
        int v = __shfl_up(y, o);
        if (lane >= o) y += v;
      }
      if (lane < 16) wtot[lane] = y;
    }
    __syncthreads();
    incl += (wave > 0) ? wtot[wave - 1] : 0;
    if (tid < B) scanOut[t * B + tid] = incl - x;
    if (tid == 1023) totals[t] = incl;
    __syncthreads();
  }

  if (tid == 0) {
    int off = 0;
    for (int t = 0; t < NTYPES; ++t) {
      const int c = totals[t];
      offs[t] = off;
      outTail[t] = (float)c;            // counts (as float values)
      outTail[NTYPES + t] = (float)off; // offsets (as float values)
      off += c;
    }
  }
}

// ---------------------------------------------------------------------------
// Kernel 3: stable scatter with LDS bucket staging.
// Phase 1: rank each atom within the block (stable), scatter its coords into
//          a type-sorted LDS buffer.
// Phase 2: copy LDS -> global. Each type's segment is contiguous in global
//          memory, so consecutive lanes write consecutive 12B triplets.
// ---------------------------------------------------------------------------
__global__ __launch_bounds__(BLOCK) void scatter_kernel(
    const float* __restrict__ coords, const int* __restrict__ types,
    const int* __restrict__ scanOut, const int* __restrict__ offs, int N,
    int B, float* __restrict__ out) {
  __shared__ float shC[CHUNK * 3];      // 48 KB type-sorted coords
  __shared__ int wtot[NTYPES][4];       // per-wave inclusive totals
  __shared__ int shOff[NTYPES + 1];     // local bucket offsets (exclusive)
  __shared__ int shDelta[NTYPES];       // 3*(globalBase[t] - shOff[t])

  const int tid = threadIdx.x;
  const int b = blockIdx.x;
  const int lane = tid & 63;
  const int wave = tid >> 6;
  const int run = b * CHUNK + tid * ITEMS;
  const bool active = (run < N);

  int ty[ITEMS];
  int cnt[NTYPES];
#pragma unroll
  for (int t = 0; t < NTYPES; ++t) cnt[t] = 0;
#pragma unroll
  for (int k = 0; k < ITEMS; ++k) ty[k] = -1;

  float c[ITEMS * 3];
  if (active) {
    const int4* p = (const int4*)(types + run);
    int4 a0 = p[0], a1 = p[1], a2 = p[2], a3 = p[3];
    int tt[ITEMS] = {a0.x, a0.y, a0.z, a0.w, a1.x, a1.y, a1.z, a1.w,
                     a2.x, a2.y, a2.z, a2.w, a3.x, a3.y, a3.z, a3.w};
#pragma unroll
    for (int k = 0; k < ITEMS; ++k) ty[k] = tt[k];
    const float4* cp = (const float4*)(coords + (size_t)run * 3);
#pragma unroll
    for (int q = 0; q < 12; ++q) {
      float4 v = cp[q];
      c[4 * q + 0] = v.x;
      c[4 * q + 1] = v.y;
      c[4 * q + 2] = v.z;
      c[4 * q + 3] = v.w;
    }
#pragma unroll
    for (int k = 0; k < ITEMS; ++k) {
#pragma unroll
      for (int t = 0; t < NTYPES; ++t) cnt[t] += (ty[k] == t) ? 1 : 0;
    }
  }

  // Wave-level stable exclusive scan per type.
  int rank[NTYPES];
#pragma unroll
  for (int t = 0; t < NTYPES; ++t) {
    int incl = cnt[t];
#pragma unroll
    for (int o = 1; o < 64; o <<= 1) {
      int v = __shfl_up(incl, o);
      if (lane >= o) incl += v;
    }
    if (lane == 63) wtot[t][wave] = incl;
    rank[t] = incl - cnt[t];  // exclusive within wave
  }
  __syncthreads();

  // Local bucket offsets + global deltas (threads 0..NTYPES-1).
  if (tid < NTYPES) {
    int loc = 0;
    for (int u = 0; u < tid; ++u)
      loc += wtot[u][0] + wtot[u][1] + wtot[u][2] + wtot[u][3];
    shOff[tid] = loc;
    shDelta[tid] = 3 * (offs[tid] + scanOut[tid * B + b] - loc);
    if (tid == NTYPES - 1) {
      shOff[NTYPES] =
          loc + wtot[tid][0] + wtot[tid][1] + wtot[tid][2] + wtot[tid][3];
    }
  }
  __syncthreads();

  // Finalize local ranks: bucket base + wave base + lane-exclusive.
#pragma unroll
  for (int t = 0; t < NTYPES; ++t) {
    int wb = 0;
#pragma unroll
    for (int w = 0; w < 3; ++w) wb += (w < wave) ? wtot[t][w] : 0;
    rank[t] += wb + shOff[t];
  }

  // Scatter coords into type-sorted LDS buffer.
  if (active) {
#pragma unroll
    for (int k = 0; k < ITEMS; ++k) {
      const int t0 = ty[k];
      int slot = 0;
#pragma unroll
      for (int t = 0; t < NTYPES; ++t) {
        if (t0 == t) {
          slot = rank[t];
          rank[t] += 1;
        }
      }
      shC[3 * slot + 0] = c[3 * k + 0];
      shC[3 * slot + 1] = c[3 * k + 1];
      shC[3 * slot + 2] = c[3 * k + 2];
    }
  }
  __syncthreads();

  // Coalesced copy-out: slot s -> global float index 3*s + delta3[type(s)].
  const int total = shOff[NTYPES];
  int offr[NTYPES];
  int dlt[NTYPES];
#pragma unroll
  for (int t = 0; t < NTYPES; ++t) {
    offr[t] = shOff[t];
    dlt[t] = shDelta[t];
  }
#pragma unroll
  for (int k = 0; k < ITEMS; ++k) {
    const int s = k * BLOCK + tid;
    if (s < total) {
      int d = dlt[0];
#pragma unroll
      for (int t = 1; t < NTYPES; ++t) d = (s >= offr[t]) ? dlt[t] : d;
      const int src = 3 * s;
      out[src + d + 0] = shC[src + 0];
      out[src + d + 1] = shC[src + 1];
      out[src + d + 2] = shC[src + 2];
    }
  }
}

extern "C" void kernel_launch(void* const* d_in, const int* in_sizes, int n_in,
                              void* d_out, int out_size, void* d_ws,
                              size_t ws_size, hipStream_t stream) {
  const float* coords = (const float*)d_in[0];
  const int* types = (const int*)d_in[1];
  const int N = in_sizes[1];              // 4,000,000 atoms
  const int B = (N + CHUNK - 1) / CHUNK;  // 977 blocks

  int* bc = (int*)d_ws;              // [NTYPES * B]
  int* scanOut = bc + NTYPES * B;    // [NTYPES * B]
  int* offs = scanOut + NTYPES * B;  // [NTYPES]
  float* out = (float*)d_out;
  float* outTail = out + (size_t)3 * N;  // counts then offsets, as floats

  hist_kernel<<<B, BLOCK, 0, stream>>>(types, N, B, bc);
  scan_kernel<<<1, 1024, 0, stream>>>(bc, B, scanOut, offs, outTail);
  scatter_kernel<<<B, BLOCK, 0, stream>>>(coords, types, scanOut, offs, N, B,
                                          out);
}